// Round 2
// baseline (17154.929 us; speedup 1.0000x reference)
//
#include <hip/hip_runtime.h>
#include <hip/hip_bf16.h>
#include <hip/hip_fp16.h>
#include <stdint.h>

#define BB 64
#define TT 512
#define II 256
#define HH 1024
#define G4 4096

typedef unsigned short u16;
typedef __attribute__((ext_vector_type(8))) _Float16 h8;
typedef __attribute__((ext_vector_type(4))) float f32x4;

__device__ __forceinline__ u16 f2h(float x){
  _Float16 h = (_Float16)x;
  return __builtin_bit_cast(u16, h);
}
__device__ __forceinline__ float h2f(u16 b){
  _Float16 h = __builtin_bit_cast(_Float16, b);
  return (float)h;
}
__device__ __forceinline__ float sigm(float x){ return 1.0f/(1.0f + __expf(-x)); }
__device__ __forceinline__ float tanh_f(float x){ return 1.0f - 2.0f/(1.0f + __expf(2.0f*x)); }

// ---------------- fp32 -> fp16 convert ----------------
__global__ void f2h_kernel(const float* __restrict__ src, u16* __restrict__ dst, int n4){
  int i = blockIdx.x*blockDim.x + threadIdx.x;
  if (i >= n4) return;
  float4 v = ((const float4*)src)[i];
  ushort4 o; o.x=f2h(v.x); o.y=f2h(v.y); o.z=f2h(v.z); o.w=f2h(v.w);
  ((ushort4*)dst)[i] = o;
}

__global__ void bias_comb_kernel(const float* __restrict__ a, const float* __restrict__ b,
                                 float* __restrict__ o, int n){
  int i = blockIdx.x*blockDim.x + threadIdx.x;
  if (i < n) o[i] = a[i] + b[i];
}

// x: [B][T][I] fp32 -> xb: [(t*B+b)][I] fp16
__global__ void xconv_kernel(const float* __restrict__ x, u16* __restrict__ xb){
  int m = blockIdx.x;            // t*BB + b
  int t = m >> 6, b = m & 63;
  const float4* src = (const float4*)(x + ((size_t)b*TT + t)*II);
  float4 v = src[threadIdx.x];   // 64 threads * 4 = 256 = II
  ushort4 o; o.x=f2h(v.x); o.y=f2h(v.y); o.z=f2h(v.z); o.w=f2h(v.w);
  ((ushort4*)(xb + (size_t)m*II))[threadIdx.x] = o;
}

// W_hh fp32 [4096][1024] -> Wsw fp16 in MFMA B-frag order.
// s = bcol*65536 + wg*32768 + ks*1024 + gg*512 + lane*8 + j
// lane=(quad*16+id); element = W_hh[(2*wg+gg)*1024 + bcol*16 + id][ks*32 + quad*8 + j]
__global__ void wswz_kernel(const float* __restrict__ Whh, u16* __restrict__ Wsw){
  int s8 = blockIdx.x*blockDim.x + threadIdx.x;   // 524288 threads, 8 elems each
  int lane = s8 & 63;
  int gg   = (s8 >> 6) & 1;
  int ks   = (s8 >> 7) & 31;
  int wg   = (s8 >> 12) & 1;
  int bcol = s8 >> 13;
  int id = lane & 15, quad = lane >> 4;
  int g = 2*wg + gg;
  const float* src = Whh + ((size_t)(g*HH + bcol*16 + id))*HH + ks*32 + quad*8;
  float4 v0 = ((const float4*)src)[0];
  float4 v1 = ((const float4*)src)[1];
  ushort4 o0, o1;
  o0.x=f2h(v0.x); o0.y=f2h(v0.y); o0.z=f2h(v0.z); o0.w=f2h(v0.w);
  o1.x=f2h(v1.x); o1.y=f2h(v1.y); o1.z=f2h(v1.z); o1.w=f2h(v1.w);
  ((ushort4*)(Wsw + (size_t)s8*8))[0] = o0;
  ((ushort4*)(Wsw + (size_t)s8*8))[1] = o1;
}

// ---------------- fp16 MFMA GEMM: C[m][n] = sum_k A[m][k]*Bt[n][k] + bias[n] ----------------
__device__ __forceinline__ void gload16(const u16* g, u16* lds){
  __builtin_amdgcn_global_load_lds((const __attribute__((address_space(1))) void*)g,
                                   (__attribute__((address_space(3))) void*)lds, 16, 0, 0);
}

__launch_bounds__(256)
__global__ void gemm_bt_kernel(const u16* __restrict__ A, const u16* __restrict__ Bt,
                               const float* __restrict__ bias, u16* __restrict__ C,
                               int M, int K){
  __shared__ __align__(16) u16 As[128*32];
  __shared__ __align__(16) u16 Bs[128*32];
  const int m0 = blockIdx.x * 128;
  const int n0 = blockIdx.y * 128;
  const int tid = threadIdx.x;
  const int wave = tid >> 6, lane = tid & 63;
  const int id = lane & 15, quad = lane >> 4;
  const int wr = wave >> 1, wc = wave & 1;    // 2x2 wave grid, 64x64 per wave
  f32x4 acc[4][4] = {};

  const int r0 = wave * 32;                    // rows this wave stages
  const int lrow = lane >> 2, lseg = (lane & 3) * 8;
  const u16* gA = A  + (size_t)(m0 + r0 + lrow)*K + lseg;
  const u16* gB = Bt + (size_t)(n0 + r0 + lrow)*K + lseg;

  for (int k0 = 0; k0 < K; k0 += 32){
    gload16(gA + k0,                  &As[(r0     )*32]);
    gload16(gA + k0 + (size_t)16*K,   &As[(r0 + 16)*32]);
    gload16(gB + k0,                  &Bs[(r0     )*32]);
    gload16(gB + k0 + (size_t)16*K,   &Bs[(r0 + 16)*32]);
    __syncthreads();
    h8 af[4], bfr[4];
    #pragma unroll
    for (int mi=0; mi<4; ++mi)
      af[mi] = *(const h8*)&As[(wr*64 + mi*16 + id)*32 + quad*8];
    #pragma unroll
    for (int nj=0; nj<4; ++nj)
      bfr[nj] = *(const h8*)&Bs[(wc*64 + nj*16 + id)*32 + quad*8];
    #pragma unroll
    for (int mi=0; mi<4; ++mi)
      #pragma unroll
      for (int nj=0; nj<4; ++nj)
        acc[mi][nj] = __builtin_amdgcn_mfma_f32_16x16x32_f16(af[mi], bfr[nj], acc[mi][nj], 0,0,0);
    __syncthreads();
  }
  #pragma unroll
  for (int mi=0; mi<4; ++mi){
    int row = m0 + wr*64 + mi*16 + quad*4;
    #pragma unroll
    for (int nj=0; nj<4; ++nj){
      int col = n0 + wc*64 + nj*16 + id;
      float bv = bias[col];
      #pragma unroll
      for (int r=0; r<4; ++r)
        C[(size_t)(row + r)*G4 + col] = f2h(acc[mi][nj][r] + bv);
    }
  }
}

// ---------------- persistent LSTM recurrence (chunk of Tc steps) ----------------
// 64 blocks x 256 threads (4 waves). Block owns 16 h-cols (j0..j0+15) = 64 gate rows.
// W streamed from global in frag order (L2-resident 128 KB/block). LDS only for
// the gate-preactivation exchange (~17 KB). Grid barrier per step.
__launch_bounds__(256)
__global__ void lstm_rec_kernel(const u16* __restrict__ xp,   // [Tc][64][4096] fp16
                                const u16* __restrict__ Wsw,  // frag-order fp16
                                u16* __restrict__ hbuf,       // 2*[64][1024] fp16
                                float* __restrict__ cst,      // [64][1024] fp32
                                u16* __restrict__ yout,       // [Tc][64][1024] or null
                                float* __restrict__ hfin,     // [64][1024] fp32
                                int* __restrict__ bar, int t0, int Tc){
  __shared__ float Gs[64*68];
  const int bcol = blockIdx.x, j0 = bcol*16;
  const int tid = threadIdx.x, wave = tid >> 6, lane = tid & 63;
  const int id = lane & 15, quad = lane >> 4;
  const int wb = wave & 1;      // batch half (32 batches)
  const int wg = wave >> 1;     // gate-row half (rows wg*32 .. +31)
  const int cb = tid >> 2, jq = tid & 3;   // cell phase: batch cb, cols j0+jq*4..+3

  const u16* Wblk = Wsw + ((size_t)bcol << 16) + ((size_t)wg << 15);

  float4 c4 = *(const float4*)&cst[(size_t)cb*HH + j0 + jq*4];

  int target = 64;
  for (int tl = 0; tl < Tc; ++tl){
    const int t = t0 + tl;
    const u16* hprev = hbuf + (size_t)(( t      & 1) << 16);
    u16*       hnext = hbuf + (size_t)(((t + 1) & 1) << 16);

    f32x4 acc[2][2] = {};
    #pragma unroll 4
    for (int ks = 0; ks < 32; ++ks){
      h8 a0 = *(const h8*)&hprev[(size_t)((wb*32      + id) << 10) + ks*32 + quad*8];
      h8 a1 = *(const h8*)&hprev[(size_t)((wb*32 + 16 + id) << 10) + ks*32 + quad*8];
      h8 b0 = *(const h8*)&Wblk[(size_t)ks*1024       + lane*8];
      h8 b1 = *(const h8*)&Wblk[(size_t)ks*1024 + 512 + lane*8];
      acc[0][0] = __builtin_amdgcn_mfma_f32_16x16x32_f16(a0, b0, acc[0][0], 0,0,0);
      acc[0][1] = __builtin_amdgcn_mfma_f32_16x16x32_f16(a0, b1, acc[0][1], 0,0,0);
      acc[1][0] = __builtin_amdgcn_mfma_f32_16x16x32_f16(a1, b0, acc[1][0], 0,0,0);
      acc[1][1] = __builtin_amdgcn_mfma_f32_16x16x32_f16(a1, b1, acc[1][1], 0,0,0);
    }
    // D layout: row(batch) = quad*4+r, col(gate idx) = id. Gs[r=g*16+jj][b]
    #pragma unroll
    for (int btl=0; btl<2; ++btl)
      #pragma unroll
      for (int gg=0; gg<2; ++gg)
        *(f32x4*)&Gs[(wg*32 + gg*16 + id)*68 + wb*32 + btl*16 + quad*4] = acc[btl][gg];
    __syncthreads();

    // cell phase: 4 cells (batch cb, j = j0 + jq*4 + jj)
    const u16* xpt = xp + (size_t)tl*(BB*G4) + (size_t)cb*G4;
    ushort4 xg0 = *(const ushort4*)&xpt[0*HH + j0 + jq*4];
    ushort4 xg1 = *(const ushort4*)&xpt[1*HH + j0 + jq*4];
    ushort4 xg2 = *(const ushort4*)&xpt[2*HH + j0 + jq*4];
    ushort4 xg3 = *(const ushort4*)&xpt[3*HH + j0 + jq*4];
    ushort4 hb4;
    float4 hf4;
    #pragma unroll
    for (int jj=0; jj<4; ++jj){
      int jl = jq*4 + jj;
      float pi = Gs[( 0 + jl)*68 + cb] + h2f(((const u16*)&xg0)[jj]);
      float pf = Gs[(16 + jl)*68 + cb] + h2f(((const u16*)&xg1)[jj]);
      float pg = Gs[(32 + jl)*68 + cb] + h2f(((const u16*)&xg2)[jj]);
      float po = Gs[(48 + jl)*68 + cb] + h2f(((const u16*)&xg3)[jj]);
      float iv = sigm(pi), fv = sigm(pf), gv = tanh_f(pg), ov = sigm(po);
      float c = fv * (&c4.x)[jj] + iv * gv;
      (&c4.x)[jj] = c;
      float h = ov * tanh_f(c);
      (&hf4.x)[jj] = h;
      ((u16*)&hb4)[jj] = f2h(h);
    }
    *(ushort4*)&hnext[(size_t)cb*HH + j0 + jq*4] = hb4;
    if (yout) *(ushort4*)&yout[(size_t)tl*(BB*HH) + (size_t)cb*HH + j0 + jq*4] = hb4;
    if (t == TT-1) *(float4*)&hfin[(size_t)cb*HH + j0 + jq*4] = hf4;

    if (tl + 1 < Tc){
      __syncthreads();
      if (tid == 0){
        __threadfence();
        __hip_atomic_fetch_add(bar, 1, __ATOMIC_ACQ_REL, __HIP_MEMORY_SCOPE_AGENT);
        while (__hip_atomic_load(bar, __ATOMIC_ACQUIRE, __HIP_MEMORY_SCOPE_AGENT) < target)
          __builtin_amdgcn_s_sleep(2);
      }
      __syncthreads();
      target += 64;
    }
  }
  *(float4*)&cst[(size_t)cb*HH + j0 + jq*4] = c4;
}

// ---------------- FC head ----------------
__global__ void fc_kernel(const float* __restrict__ hfin, const float* __restrict__ fcw,
                          const float* __restrict__ fcb, float* __restrict__ out){
  int row = blockIdx.x;          // 0..127
  int lane = threadIdx.x;        // 64
  const float* h = hfin + (size_t)row*HH;
  float a0 = 0.f, a1 = 0.f;
  for (int j = lane; j < HH; j += 64){
    float v = h[j]; v = v > 0.f ? v : 0.f;
    a0 += v * fcw[j];
    a1 += v * fcw[HH + j];
  }
  for (int off = 32; off; off >>= 1){ a0 += __shfl_down(a0, off); a1 += __shfl_down(a1, off); }
  if (lane == 0){
    out[row*2 + 0] = 1.f/(1.f + __expf(-(a0 + fcb[0])));
    out[row*2 + 1] = 1.f/(1.f + __expf(-(a1 + fcb[1])));
  }
}

// ---------------- launch ----------------
extern "C" void kernel_launch(void* const* d_in, const int* in_sizes, int n_in,
                              void* d_out, int out_size, void* d_ws, size_t ws_size,
                              hipStream_t stream){
  (void)in_sizes; (void)n_in; (void)out_size;
  const float* x    = (const float*)d_in[0];
  const float* Wih0 = (const float*)d_in[1];
  const float* Whh0 = (const float*)d_in[2];
  const float* bih0 = (const float*)d_in[3];
  const float* bhh0 = (const float*)d_in[4];
  const float* Wih1 = (const float*)d_in[5];
  const float* Whh1 = (const float*)d_in[6];
  const float* bih1 = (const float*)d_in[7];
  const float* bhh1 = (const float*)d_in[8];
  const float* fcw  = (const float*)d_in[9];
  const float* fcb  = (const float*)d_in[10];

  char* w = (char*)d_ws;
  size_t off = 0;
  auto take = [&](size_t bytes)->char*{
    char* p = w + off; off += (bytes + 255) & ~(size_t)255; return p;
  };
  u16*   xb    = (u16*)  take((size_t)TT*BB*II*2);     // 16 MB
  u16*   wih0b = (u16*)  take((size_t)G4*II*2);        // 2 MB
  u16*   wih1b = (u16*)  take((size_t)G4*HH*2);        // 8 MB
  u16*   wsw0  = (u16*)  take((size_t)G4*HH*2);        // 8 MB
  u16*   wsw1  = (u16*)  take((size_t)G4*HH*2);        // 8 MB
  float* bias0 = (float*)take(G4*4);
  float* bias1 = (float*)take(G4*4);
  u16*   hbuf0 = (u16*)  take(2*(size_t)BB*HH*2);
  u16*   hbuf1 = (u16*)  take(2*(size_t)BB*HH*2);
  float* cst0  = (float*)take((size_t)BB*HH*4);
  float* cst1  = (float*)take((size_t)BB*HH*4);
  float* hfin  = (float*)take(2*(size_t)BB*HH*4);
  int*   bar   = (int*)  take(2048);
  size_t fixedEnd = off;

  int Tc = 8;
  const int cands[6] = {512, 256, 128, 64, 32, 16};
  for (int i = 0; i < 6; ++i){
    size_t need = fixedEnd + 2*((size_t)cands[i]*BB*G4*2 + 256) + ((size_t)cands[i]*BB*HH*2 + 256);
    if (need <= ws_size){ Tc = cands[i]; break; }
  }
  u16* xp0 = (u16*)take((size_t)Tc*BB*G4*2);
  u16* xp1 = (u16*)take((size_t)Tc*BB*G4*2);
  u16* y0c = (u16*)take((size_t)Tc*BB*HH*2);
  const int nch = TT / Tc;

  hipMemsetAsync(hbuf0, 0, 2*(size_t)BB*HH*2, stream);
  hipMemsetAsync(hbuf1, 0, 2*(size_t)BB*HH*2, stream);
  hipMemsetAsync(cst0,  0, (size_t)BB*HH*4, stream);
  hipMemsetAsync(cst1,  0, (size_t)BB*HH*4, stream);
  hipMemsetAsync(bar,   0, 2048, stream);

  f2h_kernel<<<1024, 256, 0, stream>>>(Wih0, wih0b, G4*II/4);
  f2h_kernel<<<4096, 256, 0, stream>>>(Wih1, wih1b, G4*HH/4);
  bias_comb_kernel<<<16, 256, 0, stream>>>(bih0, bhh0, bias0, G4);
  bias_comb_kernel<<<16, 256, 0, stream>>>(bih1, bhh1, bias1, G4);
  xconv_kernel<<<TT*BB, 64, 0, stream>>>(x, xb);
  wswz_kernel<<<2048, 256, 0, stream>>>(Whh0, wsw0);
  wswz_kernel<<<2048, 256, 0, stream>>>(Whh1, wsw1);

  const int M = Tc * BB;
  for (int c = 0; c < nch; ++c){
    const int t0 = c * Tc;
    gemm_bt_kernel<<<dim3(M/128, 32), 256, 0, stream>>>(
        xb + (size_t)t0*BB*II, wih0b, bias0, xp0, M, II);
    lstm_rec_kernel<<<64, 256, 0, stream>>>(
        xp0, wsw0, hbuf0, cst0, y0c, hfin, bar + 2*c, t0, Tc);
    gemm_bt_kernel<<<dim3(M/128, 32), 256, 0, stream>>>(
        y0c, wih1b, bias1, xp1, M, HH);
    lstm_rec_kernel<<<64, 256, 0, stream>>>(
        xp1, wsw1, hbuf1, cst1, nullptr, hfin + (size_t)BB*HH, bar + 2*c + 1, t0, Tc);
  }
  fc_kernel<<<2*BB, 64, 0, stream>>>(hfin, fcw, fcb, (float*)d_out);
}

// Round 3
// 16961.890 us; speedup vs baseline: 1.0114x; 1.0114x over previous
//
#include <hip/hip_runtime.h>
#include <hip/hip_bf16.h>
#include <hip/hip_fp16.h>
#include <stdint.h>

#define BB 64
#define TT 512
#define II 256
#define HH 1024
#define G4 4096

typedef unsigned short u16;
typedef __attribute__((ext_vector_type(8))) _Float16 h8;
typedef __attribute__((ext_vector_type(4))) float f32x4;

__device__ __forceinline__ u16 f2h(float x){
  _Float16 h = (_Float16)x;
  return __builtin_bit_cast(u16, h);
}
__device__ __forceinline__ float sigm(float x){ return 1.0f/(1.0f + __expf(-x)); }
__device__ __forceinline__ float tanh_f(float x){ return 1.0f - 2.0f/(1.0f + __expf(2.0f*x)); }

// agent-scope (cross-XCD coherent) 16B load as two relaxed 8B atomics
__device__ __forceinline__ h8 aload16(const u16* p){
  union { unsigned long long v[2]; h8 h; } u;
  const unsigned long long* q = (const unsigned long long*)p;
  u.v[0] = __hip_atomic_load(q,     __ATOMIC_RELAXED, __HIP_MEMORY_SCOPE_AGENT);
  u.v[1] = __hip_atomic_load(q + 1, __ATOMIC_RELAXED, __HIP_MEMORY_SCOPE_AGENT);
  return u.h;
}

// ---------------- prep kernels ----------------
__global__ void bias_comb_kernel(const float* __restrict__ a, const float* __restrict__ b,
                                 float* __restrict__ o, int n){
  int i = blockIdx.x*blockDim.x + threadIdx.x;
  if (i < n) o[i] = a[i] + b[i];
}

// x: [B][T][I] fp32 -> xb: [(t*B+b)][I] fp16
__global__ void xconv_kernel(const float* __restrict__ x, u16* __restrict__ xb){
  int m = blockIdx.x;            // t*BB + b
  int t = m >> 6, b = m & 63;
  const float4* src = (const float4*)(x + ((size_t)b*TT + t)*II);
  float4 v = src[threadIdx.x];   // 64 threads * 4 = 256 = II
  ushort4 o; o.x=f2h(v.x); o.y=f2h(v.y); o.z=f2h(v.z); o.w=f2h(v.w);
  ((ushort4*)(xb + (size_t)m*II))[threadIdx.x] = o;
}

// Concat-K weight swizzle into MFMA B-frag order (fp32 -> fp16).
// dst group s8 = ((jg*KS + ks)*4 + g)*64 + lane ; element:
//   n = g*1024 + jg*16 + (lane&15), k = ks*32 + (lane>>4)*8 + j
//   src = k < Ka ? Wa[n][k] : Wb[n][k-Ka]
__global__ void wswz_kernel(const float* __restrict__ Wa, int Ka,
                            const float* __restrict__ Wb, int Kb,
                            u16* __restrict__ dst, int KS){
  int s8 = blockIdx.x*blockDim.x + threadIdx.x;
  int lane = s8 & 63;
  int g    = (s8 >> 6) & 3;
  int rest = s8 >> 8;
  int ks   = rest % KS;
  int jg   = rest / KS;
  if (jg >= 64) return;
  int id = lane & 15, quad = lane >> 4;
  int n = g*HH + jg*16 + id;
  int k = ks*32 + quad*8;
  const float* src = (k < Ka) ? (Wa + (size_t)n*Ka + k) : (Wb + (size_t)n*Kb + (k - Ka));
  float4 v0 = ((const float4*)src)[0];
  float4 v1 = ((const float4*)src)[1];
  ushort4 o0; o0.x=f2h(v0.x); o0.y=f2h(v0.y); o0.z=f2h(v0.z); o0.w=f2h(v0.w);
  ushort4 o1; o1.x=f2h(v1.x); o1.y=f2h(v1.y); o1.z=f2h(v1.z); o1.w=f2h(v1.w);
  u16* d = dst + (size_t)s8*8;
  ((ushort4*)d)[0] = o0;
  ((ushort4*)d)[1] = o1;
}

// ---------------- fused 2-layer persistent LSTM ----------------
// 128 blocks x 256 threads. blocks 0..63: layer0 (K = 256 x + 1024 h0);
// blocks 64..127: layer1 (K = 1024 y0 + 1024 h1), lagging one epoch.
// Block owns 16 h-cols (jg*16..+15) x all 64 batches; wave w = batch-tile w*16..+15.
// Weights pre-swizzled to B-frag order (normal cached loads, L2-resident —
// no L2 invalidates anywhere). h exchange via relaxed agent-scope atomics (L3-
// coherent). Grid barrier: relaxed add + relaxed poll, ordering by syncthreads.
__launch_bounds__(256, 1)
__global__ void lstm_fused_kernel(const u16* __restrict__ xb,
                                  const u16* __restrict__ Wsw0,
                                  const u16* __restrict__ Wsw1,
                                  const float* __restrict__ bias0,
                                  const float* __restrict__ bias1,
                                  u16* __restrict__ h0buf,   // 2 slots [64][1024] fp16
                                  u16* __restrict__ h1buf,   // 2 slots
                                  float* __restrict__ hfin,  // [2][64][1024] fp32
                                  int* __restrict__ bar){
  __shared__ float Gs[64*68];        // gate-rows(4g x 16j) x batches(64+pad)
  const int blk = blockIdx.x;
  const int layer = blk >> 6;
  const int jg = blk & 63;
  const int tid = threadIdx.x, wave = tid >> 6, lane = tid & 63;
  const int id = lane & 15, quad = lane >> 4;
  const int KS = layer ? 64 : 40;
  const u16* Wblk = (layer ? Wsw1 : Wsw0) + (size_t)jg * KS * 2048;
  const int ab = wave*16 + id;       // A-row (batch) this lane loads
  const int cb = tid >> 2, jq = tid & 3;  // cell phase: batch cb, j-quad jq
  const int j0 = jg * 16;
  const float* Bp = layer ? bias1 : bias0;
  float bs[4][4];
  #pragma unroll
  for (int g = 0; g < 4; ++g)
    #pragma unroll
    for (int jj = 0; jj < 4; ++jj)
      bs[g][jj] = Bp[g*HH + j0 + jq*4 + jj];
  float c4[4] = {0.f, 0.f, 0.f, 0.f};

  for (int e = 0; e <= 512; ++e){
    const bool active = layer ? (e >= 1) : (e < 512);
    if (active){
      const int t = layer ? (e - 1) : e;   // this layer's timestep
      const u16* hA0 = h0buf + ((size_t)(e & 1) << 16);        // h0[t-1] / y0[t]
      const u16* hA1 = h1buf + ((size_t)((e + 1) & 1) << 16);  // h1[t-1] (layer1)
      u16* hout = layer ? (h1buf + ((size_t)(e & 1) << 16))
                        : (h0buf + ((size_t)((e + 1) & 1) << 16));
      f32x4 acc[4] = {};
      if (layer == 0){
        const u16* xrow = xb + ((size_t)(t*64 + ab) << 8);
        #pragma unroll 4
        for (int ks = 0; ks < 8; ++ks){
          h8 a = *(const h8*)(xrow + ks*32 + quad*8);
          const u16* wp = Wblk + (size_t)ks*2048 + lane*8;
          acc[0] = __builtin_amdgcn_mfma_f32_16x16x32_f16(a, *(const h8*)(wp       ), acc[0], 0,0,0);
          acc[1] = __builtin_amdgcn_mfma_f32_16x16x32_f16(a, *(const h8*)(wp +  512), acc[1], 0,0,0);
          acc[2] = __builtin_amdgcn_mfma_f32_16x16x32_f16(a, *(const h8*)(wp + 1024), acc[2], 0,0,0);
          acc[3] = __builtin_amdgcn_mfma_f32_16x16x32_f16(a, *(const h8*)(wp + 1536), acc[3], 0,0,0);
        }
        #pragma unroll 4
        for (int ks = 8; ks < 40; ++ks){
          h8 a = aload16(hA0 + ((size_t)ab << 10) + (ks - 8)*32 + quad*8);
          const u16* wp = Wblk + (size_t)ks*2048 + lane*8;
          acc[0] = __builtin_amdgcn_mfma_f32_16x16x32_f16(a, *(const h8*)(wp       ), acc[0], 0,0,0);
          acc[1] = __builtin_amdgcn_mfma_f32_16x16x32_f16(a, *(const h8*)(wp +  512), acc[1], 0,0,0);
          acc[2] = __builtin_amdgcn_mfma_f32_16x16x32_f16(a, *(const h8*)(wp + 1024), acc[2], 0,0,0);
          acc[3] = __builtin_amdgcn_mfma_f32_16x16x32_f16(a, *(const h8*)(wp + 1536), acc[3], 0,0,0);
        }
      } else {
        #pragma unroll 4
        for (int ks = 0; ks < 32; ++ks){
          h8 a = aload16(hA0 + ((size_t)ab << 10) + ks*32 + quad*8);
          const u16* wp = Wblk + (size_t)ks*2048 + lane*8;
          acc[0] = __builtin_amdgcn_mfma_f32_16x16x32_f16(a, *(const h8*)(wp       ), acc[0], 0,0,0);
          acc[1] = __builtin_amdgcn_mfma_f32_16x16x32_f16(a, *(const h8*)(wp +  512), acc[1], 0,0,0);
          acc[2] = __builtin_amdgcn_mfma_f32_16x16x32_f16(a, *(const h8*)(wp + 1024), acc[2], 0,0,0);
          acc[3] = __builtin_amdgcn_mfma_f32_16x16x32_f16(a, *(const h8*)(wp + 1536), acc[3], 0,0,0);
        }
        #pragma unroll 4
        for (int ks = 32; ks < 64; ++ks){
          h8 a = aload16(hA1 + ((size_t)ab << 10) + (ks - 32)*32 + quad*8);
          const u16* wp = Wblk + (size_t)ks*2048 + lane*8;
          acc[0] = __builtin_amdgcn_mfma_f32_16x16x32_f16(a, *(const h8*)(wp       ), acc[0], 0,0,0);
          acc[1] = __builtin_amdgcn_mfma_f32_16x16x32_f16(a, *(const h8*)(wp +  512), acc[1], 0,0,0);
          acc[2] = __builtin_amdgcn_mfma_f32_16x16x32_f16(a, *(const h8*)(wp + 1024), acc[2], 0,0,0);
          acc[3] = __builtin_amdgcn_mfma_f32_16x16x32_f16(a, *(const h8*)(wp + 1536), acc[3], 0,0,0);
        }
      }
      // exchange: D lane(id,quad),reg r -> batch = wave*16 + quad*4 + r, gate-row = g*16 + id
      #pragma unroll
      for (int g = 0; g < 4; ++g)
        *(f32x4*)&Gs[(size_t)(g*16 + id)*68 + wave*16 + quad*4] = acc[g];
      __syncthreads();
      // cell phase: 4 cells (batch cb, j = j0 + jq*4 + jj)
      ushort4 hb; float4 hf;
      #pragma unroll
      for (int jj = 0; jj < 4; ++jj){
        int jl = jq*4 + jj;
        float pi = Gs[(     jl)*68 + cb] + bs[0][jj];
        float pf = Gs[(16 + jl)*68 + cb] + bs[1][jj];
        float pg = Gs[(32 + jl)*68 + cb] + bs[2][jj];
        float po = Gs[(48 + jl)*68 + cb] + bs[3][jj];
        float iv = sigm(pi), fv = sigm(pf), gv = tanh_f(pg), ov = sigm(po);
        float c = fv*c4[jj] + iv*gv;
        c4[jj] = c;
        float h = ov * tanh_f(c);
        (&hf.x)[jj] = h;
        ((u16*)&hb)[jj] = f2h(h);
      }
      union { ushort4 s; unsigned long long v; } pk; pk.s = hb;
      __hip_atomic_store((unsigned long long*)&hout[(size_t)cb*HH + j0 + jq*4],
                         pk.v, __ATOMIC_RELAXED, __HIP_MEMORY_SCOPE_AGENT);
      if (t == TT - 1)
        *(float4*)&hfin[(size_t)layer*(BB*HH) + (size_t)cb*HH + j0 + jq*4] = hf;
    }
    if (e < 512){
      __syncthreads();   // drains vmcnt: all h-stores ack'd at coherence point
      if (tid == 0){
        __hip_atomic_fetch_add(bar, 1, __ATOMIC_RELAXED, __HIP_MEMORY_SCOPE_AGENT);
        const int need = 128*(e + 1);
        while (__hip_atomic_load(bar, __ATOMIC_RELAXED, __HIP_MEMORY_SCOPE_AGENT) < need)
          __builtin_amdgcn_s_sleep(2);
      }
      __syncthreads();   // no loads of epoch e+1 can be hoisted above this
    }
  }
}

// ---------------- FC head ----------------
__global__ void fc_kernel(const float* __restrict__ hfin, const float* __restrict__ fcw,
                          const float* __restrict__ fcb, float* __restrict__ out){
  int row = blockIdx.x;          // 0..127  (0..63 layer0 hT, 64..127 layer1 hT)
  int lane = threadIdx.x;        // 64
  const float* h = hfin + (size_t)row*HH;
  float a0 = 0.f, a1 = 0.f;
  for (int j = lane; j < HH; j += 64){
    float v = h[j]; v = v > 0.f ? v : 0.f;
    a0 += v * fcw[j];
    a1 += v * fcw[HH + j];
  }
  for (int off = 32; off; off >>= 1){ a0 += __shfl_down(a0, off); a1 += __shfl_down(a1, off); }
  if (lane == 0){
    out[row*2 + 0] = 1.f/(1.f + __expf(-(a0 + fcb[0])));
    out[row*2 + 1] = 1.f/(1.f + __expf(-(a1 + fcb[1])));
  }
}

// ---------------- launch ----------------
extern "C" void kernel_launch(void* const* d_in, const int* in_sizes, int n_in,
                              void* d_out, int out_size, void* d_ws, size_t ws_size,
                              hipStream_t stream){
  (void)in_sizes; (void)n_in; (void)out_size; (void)ws_size;
  const float* x    = (const float*)d_in[0];
  const float* Wih0 = (const float*)d_in[1];
  const float* Whh0 = (const float*)d_in[2];
  const float* bih0 = (const float*)d_in[3];
  const float* bhh0 = (const float*)d_in[4];
  const float* Wih1 = (const float*)d_in[5];
  const float* Whh1 = (const float*)d_in[6];
  const float* bih1 = (const float*)d_in[7];
  const float* bhh1 = (const float*)d_in[8];
  const float* fcw  = (const float*)d_in[9];
  const float* fcb  = (const float*)d_in[10];

  char* w = (char*)d_ws;
  size_t off = 0;
  auto take = [&](size_t bytes)->char*{
    char* p = w + off; off += (bytes + 255) & ~(size_t)255; return p;
  };
  u16*   xb    = (u16*)  take((size_t)TT*BB*II*2);       // 16 MB
  u16*   wsw0  = (u16*)  take((size_t)G4*1280*2);        // 10 MB  (K=256+1024)
  u16*   wsw1  = (u16*)  take((size_t)G4*2048*2);        // 16 MB  (K=1024+1024)
  float* bias0 = (float*)take(G4*4);
  float* bias1 = (float*)take(G4*4);
  u16*   h0buf = (u16*)  take(2*(size_t)BB*HH*2);        // 256 KB ping-pong
  u16*   h1buf = (u16*)  take(2*(size_t)BB*HH*2);
  float* hfin  = (float*)take(2*(size_t)BB*HH*4);        // 512 KB
  int*   bar   = (int*)  take(256);

  hipMemsetAsync(h0buf, 0, 2*(size_t)BB*HH*2, stream);
  hipMemsetAsync(h1buf, 0, 2*(size_t)BB*HH*2, stream);
  hipMemsetAsync(bar,   0, 256, stream);

  bias_comb_kernel<<<16, 256, 0, stream>>>(bih0, bhh0, bias0, G4);
  bias_comb_kernel<<<16, 256, 0, stream>>>(bih1, bhh1, bias1, G4);
  xconv_kernel<<<TT*BB, 64, 0, stream>>>(x, xb);
  // L0: K=1280 (KS=40): 64*40*4*64/256 = 2560 blocks; L1: K=2048 (KS=64): 4096 blocks
  wswz_kernel<<<2560, 256, 0, stream>>>(Wih0, II, Whh0, HH, wsw0, 40);
  wswz_kernel<<<4096, 256, 0, stream>>>(Wih1, HH, Whh1, HH, wsw1, 64);

  lstm_fused_kernel<<<128, 256, 0, stream>>>(xb, wsw0, wsw1, bias0, bias1,
                                             h0buf, h1buf, hfin, bar);
  fc_kernel<<<2*BB, 64, 0, stream>>>(hfin, fcw, fcb, (float*)d_out);
}